// Round 4
// baseline (438.446 us; speedup 1.0000x reference)
//
#include <hip/hip_runtime.h>
#include <hip/hip_bf16.h>

#define B_ 32
#define T_ 2048
#define D_ 128
#define BQ 64

typedef __attribute__((ext_vector_type(8))) __bf16 bf16x8;
typedef __attribute__((ext_vector_type(16))) float f32x16;

__device__ __forceinline__ float fast_exp2(float x) {
#if __has_builtin(__builtin_amdgcn_exp2f)
    return __builtin_amdgcn_exp2f(x);
#else
    return exp2f(x);
#endif
}

__device__ __forceinline__ f32x16 zero16() {
    f32x16 z;
    #pragma unroll
    for (int i = 0; i < 16; ++i) z[i] = 0.f;
    return z;
}

// ---------- merged prep: K fp32->bf16 (same layout) + V fp32 -> VT bf16 [b][d][k] ----------
__global__ __launch_bounds__(256, 2)
void prep(const float* __restrict__ K, const float* __restrict__ V,
          const int* __restrict__ vlens,
          __hip_bfloat16* __restrict__ Kb, __hip_bfloat16* __restrict__ VTb)
{
    __shared__ float tile[64][132];               // 132: float4-aligned rows
    const int b = blockIdx.y, k0 = blockIdx.x * 64;
    const int kmax = (vlens[b] + 63) & ~63;       // main kernel never reads past ceil64
    if (k0 >= kmax) return;

    // K: straight convert, fully coalesced
    {
        const float4* src = (const float4*)(K + ((size_t)b * T_ + k0) * D_);
        uint2* dst = (uint2*)(Kb + ((size_t)b * T_ + k0) * D_);
        #pragma unroll
        for (int it = 0; it < 8; ++it) {
            int c = it * 256 + threadIdx.x;
            float4 v = src[c];
            union { __hip_bfloat16 h[4]; uint2 u; } pk;
            pk.h[0] = __float2bfloat16(v.x); pk.h[1] = __float2bfloat16(v.y);
            pk.h[2] = __float2bfloat16(v.z); pk.h[3] = __float2bfloat16(v.w);
            dst[c] = pk.u;
        }
    }
    // V: transpose through LDS (rotated reads -> 2-way banks, free)
    {
        const float4* src = (const float4*)(V + ((size_t)b * T_ + k0) * D_);
        #pragma unroll
        for (int it = 0; it < 8; ++it) {
            int c = it * 256 + threadIdx.x;
            int row = c >> 5, c4 = c & 31;
            *(float4*)&tile[row][c4 * 4] = src[c];
        }
        __syncthreads();
        #pragma unroll
        for (int it = 0; it < 8; ++it) {
            int c = it * 256 + threadIdx.x;       // 2048 chunks of 4 keys
            int kc = c & 15, d = c >> 4;
            union { __hip_bfloat16 h[4]; uint2 u; } pk;
            #pragma unroll
            for (int j = 0; j < 4; ++j) {
                int jj = (j + kc) & 3;            // rotate to spread LDS banks
                pk.h[jj] = __float2bfloat16(tile[kc * 4 + jj][d]);
            }
            *(uint2*)(VTb + ((size_t)b * D_ + d) * T_ + k0 + kc * 4) = pk.u;
        }
    }
}

// ---------- main: flash attention, 2 waves x 32 q-rows, 32x32x16 MFMA ----------
// Register-prefetch pipeline: tile kb+1's global loads are in flight during
// tile kb's compute; LDS stays single-buffered (44 KB -> 3 blocks/CU).
__global__ __launch_bounds__(128, 2)
void attn_main(const float* __restrict__ Q, const int* __restrict__ vlens,
               const __hip_bfloat16* __restrict__ Kb,
               const __hip_bfloat16* __restrict__ VTb,
               float* __restrict__ out)
{
    const int tid  = threadIdx.x;
    const int wave = tid >> 6;
    const int lane = tid & 63;
    const int l32  = lane & 31;
    const int hi   = lane >> 5;

    // batch-fastest grid: consecutive blocks span all 32 vlens (CU load balance)
    const int b    = blockIdx.x;
    const int q0   = blockIdx.y * BQ;
    const int vlen = vlens[b];
    const int nkb  = (vlen + 63) >> 6;

    __shared__ __hip_bfloat16 sK [64][136];   // [key][d]   (conflict-free, verified 0)
    __shared__ __hip_bfloat16 sVT[128][72];   // [d][key]
    __shared__ __hip_bfloat16 sP [64][72];    // [q][key], wave-private halves

    // Q A-frags: A[m=lane&31][k=hi*8+j], 8 d-steps, in registers
    bf16x8 qf[8];
    {
        const float* qp = Q + ((size_t)b * T_ + q0 + wave * 32 + l32) * D_ + hi * 8;
        #pragma unroll
        for (int ds = 0; ds < 8; ++ds) {
            const float4* p4 = (const float4*)(qp + ds * 16);
            float4 a = p4[0], c = p4[1];
            __hip_bfloat16 h[8] = {
                __float2bfloat16(a.x), __float2bfloat16(a.y),
                __float2bfloat16(a.z), __float2bfloat16(a.w),
                __float2bfloat16(c.x), __float2bfloat16(c.y),
                __float2bfloat16(c.z), __float2bfloat16(c.w) };
            qf[ds] = *(const bf16x8*)h;
        }
    }

    bf16x8 ones;
    #pragma unroll
    for (int j = 0; j < 8; ++j) ones[j] = (__bf16)1.0f;

    f32x16 o[4];
    #pragma unroll
    for (int dt = 0; dt < 4; ++dt) o[dt] = zero16();
    f32x16 lacc = zero16();

    const float C = 1.4426950408889634f / 256.0f;   // log2(e)/(2*d)

    const __hip_bfloat16* kb_base = Kb + (size_t)b * T_ * D_;
    const __hip_bfloat16* vt_base = VTb + (size_t)b * D_ * T_;

    // ---- register prefetch buffers (16 x uint4 = 64 VGPRs) ----
    uint4 kpf[8], vpf[8];
    #define ISSUE(KB)                                                          \
        do {                                                                   \
            const __hip_bfloat16* kbp = kb_base + (size_t)(KB) * 64 * D_;      \
            _Pragma("unroll")                                                  \
            for (int it = 0; it < 8; ++it) {                                   \
                int c = it * 128 + tid;                                        \
                int row = c >> 4, cc = c & 15;                                 \
                kpf[it] = *(const uint4*)(kbp + row * D_ + cc * 8);            \
            }                                                                  \
            const __hip_bfloat16* vbp = vt_base + (KB) * 64;                   \
            _Pragma("unroll")                                                  \
            for (int it = 0; it < 8; ++it) {                                   \
                int c = it * 128 + tid;                                        \
                int d = c >> 3, cc = c & 7;                                    \
                vpf[it] = *(const uint4*)(vbp + (size_t)d * T_ + cc * 8);      \
            }                                                                  \
        } while (0)

    if (nkb > 0) ISSUE(0);

    for (int kb = 0; kb < nkb; ++kb) {
        const int k0 = kb * 64;
        __syncthreads();                 // previous iter's LDS reads done

        // commit prefetched tile to LDS (vmcnt waits inserted here)
        #pragma unroll
        for (int it = 0; it < 8; ++it) {
            int c = it * 128 + tid;
            int row = c >> 4, cc = c & 15;
            *(uint4*)&sK[row][cc * 8] = kpf[it];
        }
        #pragma unroll
        for (int it = 0; it < 8; ++it) {
            int c = it * 128 + tid;
            int d = c >> 3, cc = c & 7;
            *(uint4*)&sVT[d][cc * 8] = vpf[it];
        }
        // launch next tile's loads; they fly during this tile's compute
        if (kb + 1 < nkb) ISSUE(kb + 1);
        __syncthreads();                 // tile visible to both waves

        // ---- S = Q K^T : 2 key-tiles x 8 d-steps ----
        f32x16 s[2];
        s[0] = zero16(); s[1] = zero16();
        #pragma unroll
        for (int nt = 0; nt < 2; ++nt)
            #pragma unroll
            for (int ds = 0; ds < 8; ++ds) {
                bf16x8 kf = *(const bf16x8*)&sK[nt * 32 + l32][ds * 16 + hi * 8];
                s[nt] = __builtin_amdgcn_mfma_f32_32x32x16_bf16(qf[ds], kf, s[nt], 0, 0, 0);
            }

        // ---- p = exp2(s*C), mask -> 0, scatter to sP (wave-private rows) ----
        #pragma unroll
        for (int nt = 0; nt < 2; ++nt) {
            const bool valid = (k0 + nt * 32 + l32) < vlen;
            #pragma unroll
            for (int r = 0; r < 16; ++r) {
                float e = fast_exp2(s[nt][r] * C);
                e = valid ? e : 0.f;
                int q = (r & 3) + 8 * (r >> 2) + 4 * hi + wave * 32;
                sP[q][nt * 32 + l32] = __float2bfloat16(e);
            }
        }
        // sP rows are wave-private: same-wave LDS ordering suffices, no barrier.

        // ---- O += P V ; lacc += P * 1 ----
        #pragma unroll
        for (int ks = 0; ks < 4; ++ks) {
            bf16x8 pf = *(const bf16x8*)&sP[wave * 32 + l32][ks * 16 + hi * 8];
            lacc = __builtin_amdgcn_mfma_f32_32x32x16_bf16(pf, ones, lacc, 0, 0, 0);
            #pragma unroll
            for (int dt = 0; dt < 4; ++dt) {
                bf16x8 vf = *(const bf16x8*)&sVT[dt * 32 + l32][ks * 16 + hi * 8];
                o[dt] = __builtin_amdgcn_mfma_f32_32x32x16_bf16(pf, vf, o[dt], 0, 0, 0);
            }
        }
    }
    #undef ISSUE

    // ---- epilogue: O / l ; fully-masked (l==0) -> zeros ----
    float inv[16];
    #pragma unroll
    for (int r = 0; r < 16; ++r) inv[r] = (lacc[r] > 0.f) ? 1.0f / lacc[r] : 0.f;
    #pragma unroll
    for (int dt = 0; dt < 4; ++dt)
        #pragma unroll
        for (int r = 0; r < 16; ++r) {
            int q = (r & 3) + 8 * (r >> 2) + 4 * hi + wave * 32;
            out[((size_t)b * T_ + q0 + q) * D_ + dt * 32 + l32] = o[dt][r] * inv[r];
        }
}

extern "C" void kernel_launch(void* const* d_in, const int* in_sizes, int n_in,
                              void* d_out, int out_size, void* d_ws, size_t ws_size,
                              hipStream_t stream) {
    const float* Q = (const float*)d_in[0];
    const float* K = (const float*)d_in[1];
    const float* V = (const float*)d_in[2];
    const int* vl  = (const int*)d_in[3];
    float* out     = (float*)d_out;

    // ws: Kb bf16 [B][T][D] (16 MiB) | VTb bf16 [B][D][T] (16 MiB)
    const size_t kb_bytes = (size_t)B_ * T_ * D_ * 2;
    if (ws_size < 2 * kb_bytes) return;   // zeroed out -> absmax 0.3047 signature
    __hip_bfloat16* Kb  = (__hip_bfloat16*)d_ws;
    __hip_bfloat16* VTb = (__hip_bfloat16*)((char*)d_ws + kb_bytes);

    prep<<<dim3(T_ / 64, B_), 256, 0, stream>>>(K, V, vl, Kb, VTb);
    attn_main<<<dim3(B_, T_ / BQ), 128, 0, stream>>>(Q, vl, Kb, VTb, out);
}

// Round 5
// 265.341 us; speedup vs baseline: 1.6524x; 1.6524x over previous
//
#include <hip/hip_runtime.h>
#include <hip/hip_bf16.h>

#define B_ 32
#define T_ 2048
#define D_ 128
#define BQ 64

typedef __attribute__((ext_vector_type(8))) __bf16 bf16x8;
typedef __attribute__((ext_vector_type(16))) float f32x16;

#define GLB_AS __attribute__((address_space(1)))
#define LDS_AS __attribute__((address_space(3)))

__device__ __forceinline__ float fast_exp2(float x) {
#if __has_builtin(__builtin_amdgcn_exp2f)
    return __builtin_amdgcn_exp2f(x);
#else
    return exp2f(x);
#endif
}

__device__ __forceinline__ f32x16 zero16() {
    f32x16 z;
    #pragma unroll
    for (int i = 0; i < 16; ++i) z[i] = 0.f;
    return z;
}

// async global->LDS, 16B per lane, dest = uniform base + lane*16 (m97-verified)
__device__ __forceinline__ void dma16(const __hip_bfloat16* g, __hip_bfloat16* l) {
    __builtin_amdgcn_global_load_lds((const GLB_AS uint4*)g, (LDS_AS uint4*)l, 16, 0, 0);
}

// ---------- prep: K fp32->bf16 (same layout) + V fp32 -> VT bf16 [b][d][k] ----------
__global__ __launch_bounds__(256, 2)
void prep(const float* __restrict__ K, const float* __restrict__ V,
          const int* __restrict__ vlens,
          __hip_bfloat16* __restrict__ Kb, __hip_bfloat16* __restrict__ VTb)
{
    __shared__ float tile[64][132];
    const int b = blockIdx.y, k0 = blockIdx.x * 64;
    const int kmax = (vlens[b] + 63) & ~63;
    if (k0 >= kmax) return;

    {   // K: straight convert, coalesced
        const float4* src = (const float4*)(K + ((size_t)b * T_ + k0) * D_);
        uint2* dst = (uint2*)(Kb + ((size_t)b * T_ + k0) * D_);
        #pragma unroll
        for (int it = 0; it < 8; ++it) {
            int c = it * 256 + threadIdx.x;
            float4 v = src[c];
            union { __hip_bfloat16 h[4]; uint2 u; } pk;
            pk.h[0] = __float2bfloat16(v.x); pk.h[1] = __float2bfloat16(v.y);
            pk.h[2] = __float2bfloat16(v.z); pk.h[3] = __float2bfloat16(v.w);
            dst[c] = pk.u;
        }
    }
    {   // V: transpose through LDS
        const float4* src = (const float4*)(V + ((size_t)b * T_ + k0) * D_);
        #pragma unroll
        for (int it = 0; it < 8; ++it) {
            int c = it * 256 + threadIdx.x;
            int row = c >> 5, c4 = c & 31;
            *(float4*)&tile[row][c4 * 4] = src[c];
        }
        __syncthreads();
        #pragma unroll
        for (int it = 0; it < 8; ++it) {
            int c = it * 256 + threadIdx.x;
            int kc = c & 15, d = c >> 4;
            union { __hip_bfloat16 h[4]; uint2 u; } pk;
            #pragma unroll
            for (int j = 0; j < 4; ++j) {
                int jj = (j + kc) & 3;
                pk.h[jj] = __float2bfloat16(tile[kc * 4 + jj][d]);
            }
            *(uint2*)(VTb + ((size_t)b * D_ + d) * T_ + k0 + kc * 4) = pk.u;
        }
    }
}

// ---------- main: flash attention, async-DMA double-buffered K-loop ----------
// LDS tiles are UNPADDED (global_load_lds needs lane-contiguous dest); bank
// conflicts broken by XOR swizzle applied to the *global source* chunk index:
// LDS chunk (r,c) holds global 16B-chunk (c ^ (r&7)). Reads apply the same XOR.
__global__ __launch_bounds__(128, 2)
void attn_main(const float* __restrict__ Q, const int* __restrict__ vlens,
               const __hip_bfloat16* __restrict__ Kb,
               const __hip_bfloat16* __restrict__ VTb,
               float* __restrict__ out)
{
    const int tid  = threadIdx.x;
    const int wave = tid >> 6;
    const int lane = tid & 63;
    const int l32  = lane & 31;
    const int hi   = lane >> 5;

    const int b    = blockIdx.x;          // batch-fastest: CU load balance
    const int q0   = blockIdx.y * BQ;
    const int vlen = vlens[b];
    const int nkb  = (vlen + 63) >> 6;

    __shared__ __hip_bfloat16 sK [2][64 * 128];   // [buf][key][d]  16 KB each
    __shared__ __hip_bfloat16 sVT[2][128 * 64];   // [buf][d][key]  16 KB each
    __shared__ __hip_bfloat16 sP [64][72];        // [q][key], padded, wave-private

    const __hip_bfloat16* kb_base = Kb + (size_t)b * T_ * D_;
    const __hip_bfloat16* vt_base = VTb + (size_t)b * D_ * T_;

    // issue one tile's DMA: 16 instrs/wave, 32 KB total, swizzled source chunks
    auto issue = [&](int t, int buf) {
        const __hip_bfloat16* kt = kb_base + (size_t)t * 64 * D_;
        const __hip_bfloat16* vt = vt_base + t * 64;
        __hip_bfloat16* dk = &sK[buf][0];
        __hip_bfloat16* dv = &sVT[buf][0];
        #pragma unroll
        for (int i = 0; i < 8; ++i) {
            int f = wave * 512 + i * 64 + lane;     // flat 16B chunk 0..1023
            int r = f >> 4, c = f & 15;             // 64 rows x 16 chunks
            int cg = c ^ (r & 7);
            dma16(kt + r * D_ + cg * 8, dk + (wave * 512 + i * 64) * 8);
        }
        #pragma unroll
        for (int i = 0; i < 8; ++i) {
            int f = wave * 512 + i * 64 + lane;
            int r = f >> 3, c = f & 7;              // 128 rows x 8 chunks
            int cg = c ^ (r & 7);
            dma16(vt + (size_t)r * T_ + cg * 8, dv + (wave * 512 + i * 64) * 8);
        }
    };

    if (nkb > 0) issue(0, 0);

    // Q A-frags: A[m=lane&31][k=hi*8+j], loads fly alongside tile-0 DMA
    bf16x8 qf[8];
    {
        const float* qp = Q + ((size_t)b * T_ + q0 + wave * 32 + l32) * D_ + hi * 8;
        #pragma unroll
        for (int ds = 0; ds < 8; ++ds) {
            const float4* p4 = (const float4*)(qp + ds * 16);
            float4 a = p4[0], c = p4[1];
            __hip_bfloat16 h[8] = {
                __float2bfloat16(a.x), __float2bfloat16(a.y),
                __float2bfloat16(a.z), __float2bfloat16(a.w),
                __float2bfloat16(c.x), __float2bfloat16(c.y),
                __float2bfloat16(c.z), __float2bfloat16(c.w) };
            qf[ds] = *(const bf16x8*)h;
        }
    }

    bf16x8 ones;
    #pragma unroll
    for (int j = 0; j < 8; ++j) ones[j] = (__bf16)1.0f;

    f32x16 o[4];
    #pragma unroll
    for (int dt = 0; dt < 4; ++dt) o[dt] = zero16();
    f32x16 lacc = zero16();

    const float C = 1.4426950408889634f / 256.0f;   // log2(e)/(2*d)

    for (int kb = 0; kb < nkb; ++kb) {
        const int cur = kb & 1;
        const int k0  = kb * 64;

        // __syncthreads' implicit vmcnt(0) drain IS the tile-kb-ready wait:
        // tile kb's DMAs were issued one full compute phase ago.
        __syncthreads();
        if (kb + 1 < nkb) issue(kb + 1, cur ^ 1);   // flies during this compute

        const __hip_bfloat16* sKc = &sK[cur][0];
        const __hip_bfloat16* sVc = &sVT[cur][0];

        // ---- S = Q K^T : 2 key-tiles x 8 d-steps (swizzled reads) ----
        f32x16 s[2];
        s[0] = zero16(); s[1] = zero16();
        #pragma unroll
        for (int nt = 0; nt < 2; ++nt) {
            const int row = nt * 32 + l32;
            #pragma unroll
            for (int ds = 0; ds < 8; ++ds) {
                bf16x8 kf = *(const bf16x8*)(sKc + row * 128 + (((ds * 2 + hi) ^ (l32 & 7)) * 8));
                s[nt] = __builtin_amdgcn_mfma_f32_32x32x16_bf16(qf[ds], kf, s[nt], 0, 0, 0);
            }
        }

        // ---- p = exp2(s*C), mask -> 0, scatter to sP (wave-private rows) ----
        #pragma unroll
        for (int nt = 0; nt < 2; ++nt) {
            const bool valid = (k0 + nt * 32 + l32) < vlen;
            #pragma unroll
            for (int r = 0; r < 16; ++r) {
                float e = fast_exp2(s[nt][r] * C);
                e = valid ? e : 0.f;
                int q = (r & 3) + 8 * (r >> 2) + 4 * hi + wave * 32;
                sP[q][nt * 32 + l32] = __float2bfloat16(e);
            }
        }
        // sP rows are wave-private: same-wave DS ordering suffices, no barrier.

        // ---- O += P V ; lacc += P * 1 (row-sums via ones-fragment) ----
        #pragma unroll
        for (int ks = 0; ks < 4; ++ks) {
            bf16x8 pf = *(const bf16x8*)&sP[wave * 32 + l32][ks * 16 + hi * 8];
            lacc = __builtin_amdgcn_mfma_f32_32x32x16_bf16(pf, ones, lacc, 0, 0, 0);
            #pragma unroll
            for (int dt = 0; dt < 4; ++dt) {
                const int row = dt * 32 + l32;
                bf16x8 vf = *(const bf16x8*)(sVc + row * 64 + (((ks * 2 + hi) ^ (l32 & 7)) * 8));
                o[dt] = __builtin_amdgcn_mfma_f32_32x32x16_bf16(pf, vf, o[dt], 0, 0, 0);
            }
        }
    }

    // ---- epilogue: O / l ; fully-masked (l==0) -> zeros ----
    float inv[16];
    #pragma unroll
    for (int r = 0; r < 16; ++r) inv[r] = (lacc[r] > 0.f) ? 1.0f / lacc[r] : 0.f;
    #pragma unroll
    for (int dt = 0; dt < 4; ++dt)
        #pragma unroll
        for (int r = 0; r < 16; ++r) {
            int q = (r & 3) + 8 * (r >> 2) + 4 * hi + wave * 32;
            out[((size_t)b * T_ + q0 + q) * D_ + dt * 32 + l32] = o[dt][r] * inv[r];
        }
}

extern "C" void kernel_launch(void* const* d_in, const int* in_sizes, int n_in,
                              void* d_out, int out_size, void* d_ws, size_t ws_size,
                              hipStream_t stream) {
    const float* Q = (const float*)d_in[0];
    const float* K = (const float*)d_in[1];
    const float* V = (const float*)d_in[2];
    const int* vl  = (const int*)d_in[3];
    float* out     = (float*)d_out;

    // ws: Kb bf16 [B][T][D] (16 MiB) | VTb bf16 [B][D][T] (16 MiB)
    const size_t kb_bytes = (size_t)B_ * T_ * D_ * 2;
    if (ws_size < 2 * kb_bytes) return;   // zeroed out -> absmax 0.3047 signature
    __hip_bfloat16* Kb  = (__hip_bfloat16*)d_ws;
    __hip_bfloat16* VTb = (__hip_bfloat16*)((char*)d_ws + kb_bytes);

    prep<<<dim3(T_ / 64, B_), 256, 0, stream>>>(K, V, vl, Kb, VTb);
    attn_main<<<dim3(B_, T_ / BQ), 128, 0, stream>>>(Q, vl, Kb, VTb, out);
}